// Round 1
// baseline (1089.599 us; speedup 1.0000x reference)
//
#include <hip/hip_runtime.h>

#define N_NODES 100000
#define N_EDGES 1600000
#define F 128

// ---------------- CSR build ----------------

__global__ void k_hist(const int* __restrict__ dst, int* __restrict__ cnt) {
    int i = blockIdx.x * blockDim.x + threadIdx.x;
    if (i < N_EDGES) atomicAdd(&cnt[dst[i]], 1);
}

// single-block exclusive scan of cnt[N_NODES] -> row_ptr[N_NODES+1]
__global__ void k_scan(const int* __restrict__ cnt, int* __restrict__ row_ptr) {
    __shared__ int sums[1024];
    const int t = threadIdx.x;
    const int CH = (N_NODES + 1023) / 1024;  // 98
    int beg = t * CH;
    int end = beg + CH; if (end > N_NODES) end = N_NODES;
    int s = 0;
    for (int i = beg; i < end; ++i) s += cnt[i];
    sums[t] = s;
    __syncthreads();
    // Hillis-Steele inclusive scan
    for (int off = 1; off < 1024; off <<= 1) {
        int v = (t >= off) ? sums[t - off] : 0;
        __syncthreads();
        sums[t] += v;
        __syncthreads();
    }
    int run = (t == 0) ? 0 : sums[t - 1];
    for (int i = beg; i < end; ++i) { row_ptr[i] = run; run += cnt[i]; }
    if (t == 1023) row_ptr[N_NODES] = run;  // == N_EDGES
}

__global__ void k_fill(const int* __restrict__ src, const int* __restrict__ dst,
                       const int* __restrict__ row_ptr, int* __restrict__ cursor,
                       int* __restrict__ col) {
    int i = blockIdx.x * blockDim.x + threadIdx.x;
    if (i < N_EDGES) {
        int d = dst[i];
        int pos = row_ptr[d] + atomicAdd(&cursor[d], 1);
        col[pos] = src[i];
    }
}

// ---------------- mean aggregation: one wave per node ----------------

__global__ void k_agg(const float* __restrict__ h, const int* __restrict__ row_ptr,
                      const int* __restrict__ col, float* __restrict__ out) {
    int node = (blockIdx.x * blockDim.x + threadIdx.x) >> 6;
    if (node >= N_NODES) return;
    int lane = threadIdx.x & 63;
    int beg = row_ptr[node], end = row_ptr[node + 1];
    float2 acc = make_float2(0.f, 0.f);
    for (int e = beg; e < end; ++e) {
        int s = col[e];  // wave-uniform -> scalar load
        float2 v = *reinterpret_cast<const float2*>(h + (size_t)s * F + lane * 2);
        acc.x += v.x; acc.y += v.y;
    }
    int deg = end - beg;
    float inv = 1.0f / (float)(deg > 0 ? deg : 1);
    float2 r = make_float2(acc.x * inv, acc.y * inv);
    *reinterpret_cast<float2*>(out + (size_t)node * F + lane * 2) = r;
}

// ---------------- fused layer: out = A0@W0^T (+ A1@W1^T) + b, optional ReLU ----
// block: 256 threads, tile = 64 nodes x 128 out-features.
// thread (tn = t>>4 in 0..15, tf = t&15): nodes tn*4+i (i<4), feats j*16+tf (j<8).

template <bool RELU, bool TWO>
__global__ __launch_bounds__(256) void k_layer(
        const float* __restrict__ A0, const float* __restrict__ A1,
        const float* __restrict__ W0, const float* __restrict__ W1,
        const float* __restrict__ bias, float* __restrict__ out) {
    __shared__ float sA[64][132];    // +4 pad: float4-aligned rows, <=2-way conflicts
    __shared__ float sW[128][132];

    const int t = threadIdx.x;
    const int node0 = blockIdx.x * 64;
    const int tn = t >> 4;
    const int tf = t & 15;

    float acc[4][8];
#pragma unroll
    for (int i = 0; i < 4; ++i)
#pragma unroll
        for (int j = 0; j < 8; ++j) acc[i][j] = 0.f;

    const int nphase = TWO ? 2 : 1;
    for (int ph = 0; ph < nphase; ++ph) {
        const float* __restrict__ A = (ph == 0) ? A0 : A1;
        const float* __restrict__ W = (ph == 0) ? W0 : W1;
        if (ph) __syncthreads();  // previous phase's LDS reads done

        // stage A tile: 64x128 floats = 2048 float4, 8 per thread
#pragma unroll
        for (int r = 0; r < 8; ++r) {
            int fi = t + 256 * r;
            int row = fi >> 5;        // 32 float4 per row
            int cf = fi & 31;
            int rowg = node0 + row;
            if (rowg > N_NODES - 1) rowg = N_NODES - 1;
            *reinterpret_cast<float4*>(&sA[row][cf * 4]) =
                *reinterpret_cast<const float4*>(&A[(size_t)rowg * F + cf * 4]);
        }
        // stage W tile: 128x128 floats = 4096 float4, 16 per thread
#pragma unroll
        for (int r = 0; r < 16; ++r) {
            int fi = t + 256 * r;
            int row = fi >> 5;
            int cf = fi & 31;
            *reinterpret_cast<float4*>(&sW[row][cf * 4]) =
                *reinterpret_cast<const float4*>(&W[(size_t)row * F + cf * 4]);
        }
        __syncthreads();

#pragma unroll 4
        for (int k0 = 0; k0 < 128; k0 += 4) {
            float4 av[4], bv[8];
#pragma unroll
            for (int i = 0; i < 4; ++i)
                av[i] = *reinterpret_cast<const float4*>(&sA[tn * 4 + i][k0]);
#pragma unroll
            for (int j = 0; j < 8; ++j)
                bv[j] = *reinterpret_cast<const float4*>(&sW[j * 16 + tf][k0]);
#pragma unroll
            for (int i = 0; i < 4; ++i)
#pragma unroll
                for (int j = 0; j < 8; ++j)
                    acc[i][j] += av[i].x * bv[j].x + av[i].y * bv[j].y +
                                 av[i].z * bv[j].z + av[i].w * bv[j].w;
        }
    }

    // epilogue
#pragma unroll
    for (int i = 0; i < 4; ++i) {
        int node = node0 + tn * 4 + i;
        if (node >= N_NODES) continue;
#pragma unroll
        for (int j = 0; j < 8; ++j) {
            int f = j * 16 + tf;
            float v = acc[i][j] + bias[f];
            if (RELU) v = fmaxf(v, 0.f);
            out[(size_t)node * F + f] = v;
        }
    }
}

// ---------------- launcher ----------------

extern "C" void kernel_launch(void* const* d_in, const int* in_sizes, int n_in,
                              void* d_out, int out_size, void* d_ws, size_t ws_size,
                              hipStream_t stream) {
    const float* x   = (const float*)d_in[0];
    const int*   src = (const int*)d_in[1];
    const int*   dst = (const int*)d_in[2];
    const float* W1s = (const float*)d_in[3];
    const float* W1n = (const float*)d_in[4];
    const float* b1  = (const float*)d_in[5];
    const float* W2s = (const float*)d_in[6];
    const float* W2n = (const float*)d_in[7];
    const float* b2  = (const float*)d_in[8];
    const float* W3  = (const float*)d_in[9];
    const float* b3  = (const float*)d_in[10];
    float* out = (float*)d_out;

    // workspace layout (~110 MB)
    char* p = (char*)d_ws;
    auto align512 = [](size_t v) { return (v + 511) & ~(size_t)511; };
    int* row_ptr = (int*)p;   p += align512((N_NODES + 1) * sizeof(int));
    int* cnt     = (int*)p;   p += align512((size_t)N_NODES * sizeof(int));
    int* col     = (int*)p;   p += align512((size_t)N_EDGES * sizeof(int));
    float* agg   = (float*)p; p += (size_t)N_NODES * F * sizeof(float);
    float* h1    = (float*)p; p += (size_t)N_NODES * F * sizeof(float);

    // CSR build (in-edges keyed by dst)
    hipMemsetAsync(cnt, 0, (size_t)N_NODES * sizeof(int), stream);
    k_hist<<<(N_EDGES + 255) / 256, 256, 0, stream>>>(dst, cnt);
    k_scan<<<1, 1024, 0, stream>>>(cnt, row_ptr);
    hipMemsetAsync(cnt, 0, (size_t)N_NODES * sizeof(int), stream);  // cursors
    k_fill<<<(N_EDGES + 255) / 256, 256, 0, stream>>>(src, dst, row_ptr, cnt, col);

    const int agg_grid = (N_NODES + 3) / 4;       // 4 waves (nodes) per 256-thr block
    const int gemm_grid = (N_NODES + 63) / 64;

    // layer 1: h1 = relu(x@W1s^T + agg(x)@W1n^T + b1)
    k_agg<<<agg_grid, 256, 0, stream>>>(x, row_ptr, col, agg);
    k_layer<true, true><<<gemm_grid, 256, 0, stream>>>(x, agg, W1s, W1n, b1, h1);

    // layer 2: h2 = h1@W2s^T + agg(h1)@W2n^T + b2   (written in-place over agg)
    k_agg<<<agg_grid, 256, 0, stream>>>(h1, row_ptr, col, agg);
    k_layer<false, true><<<gemm_grid, 256, 0, stream>>>(h1, agg, W2s, W2n, b2, agg);

    // layer 3: out = h2@W3^T + b3
    k_layer<false, false><<<gemm_grid, 256, 0, stream>>>(agg, nullptr, W3, nullptr, b3, out);
}

// Round 2
// 761.940 us; speedup vs baseline: 1.4300x; 1.4300x over previous
//
#include <hip/hip_runtime.h>

#define N_NODES 100000
#define N_EDGES 1600000
#define F 128

typedef short short8 __attribute__((ext_vector_type(8)));   // 8 bf16 (4 VGPR)
typedef float f32x4 __attribute__((ext_vector_type(4)));
typedef unsigned short ushort_t;
typedef ushort_t ushort8 __attribute__((ext_vector_type(8)));

__device__ __forceinline__ ushort_t f2b(float f) {
    union { float f; unsigned u; } v; v.f = f;
    unsigned r = v.u + 0x7fff + ((v.u >> 16) & 1);   // RNE
    return (ushort_t)(r >> 16);
}
__device__ __forceinline__ float b2f(ushort_t b) {
    union { unsigned u; float f; } v; v.u = ((unsigned)b) << 16;
    return v.f;
}

// ---------------- CSR build ----------------

__global__ void k_hist(const int* __restrict__ dst, int* __restrict__ cnt) {
    int i = blockIdx.x * blockDim.x + threadIdx.x;
    if (i < N_EDGES) atomicAdd(&cnt[dst[i]], 1);
}

__global__ void k_scan(const int* __restrict__ cnt, int* __restrict__ row_ptr) {
    __shared__ int sums[1024];
    const int t = threadIdx.x;
    const int CH = (N_NODES + 1023) / 1024;
    int beg = t * CH;
    int end = beg + CH; if (end > N_NODES) end = N_NODES;
    int s = 0;
    for (int i = beg; i < end; ++i) s += cnt[i];
    sums[t] = s;
    __syncthreads();
    for (int off = 1; off < 1024; off <<= 1) {
        int v = (t >= off) ? sums[t - off] : 0;
        __syncthreads();
        sums[t] += v;
        __syncthreads();
    }
    int run = (t == 0) ? 0 : sums[t - 1];
    for (int i = beg; i < end; ++i) { row_ptr[i] = run; run += cnt[i]; }
    if (t == 1023) row_ptr[N_NODES] = run;
}

__global__ void k_fill(const int* __restrict__ src, const int* __restrict__ dst,
                       const int* __restrict__ row_ptr, int* __restrict__ cursor,
                       int* __restrict__ col) {
    int i = blockIdx.x * blockDim.x + threadIdx.x;
    if (i < N_EDGES) {
        int d = dst[i];
        int pos = row_ptr[d] + atomicAdd(&cursor[d], 1);
        col[pos] = src[i];
    }
}

// ---------------- conversions ----------------

__global__ void k_cvt(const float* __restrict__ in, ushort_t* __restrict__ out, int n8) {
    int i = blockIdx.x * blockDim.x + threadIdx.x;
    if (i >= n8) return;
    const float4* p = reinterpret_cast<const float4*>(in) + (size_t)i * 2;
    float4 a = p[0], b = p[1];
    ushort8 r;
    r[0] = f2b(a.x); r[1] = f2b(a.y); r[2] = f2b(a.z); r[3] = f2b(a.w);
    r[4] = f2b(b.x); r[5] = f2b(b.y); r[6] = f2b(b.z); r[7] = f2b(b.w);
    *reinterpret_cast<ushort8*>(out + (size_t)i * 8) = r;
}

__global__ void k_cvtw(const float* __restrict__ a, const float* __restrict__ b,
                       const float* __restrict__ c, const float* __restrict__ d,
                       const float* __restrict__ e, ushort_t* __restrict__ out) {
    int i = blockIdx.x * blockDim.x + threadIdx.x;
    if (i >= 5 * F * F) return;
    const float* srcs[5] = {a, b, c, d, e};
    out[i] = f2b(srcs[i >> 14][i & (F * F - 1)]);
}

// ---------------- mean aggregation: one wave per node, bf16 rows ----------------

__global__ void k_agg(const ushort_t* __restrict__ h, const int* __restrict__ row_ptr,
                      const int* __restrict__ col, ushort_t* __restrict__ out) {
    int node = (blockIdx.x * blockDim.x + threadIdx.x) >> 6;
    if (node >= N_NODES) return;
    int lane = threadIdx.x & 63;
    int beg = row_ptr[node], end = row_ptr[node + 1];
    float ax = 0.f, ay = 0.f;
    for (int e = beg; e < end; ++e) {
        int s = col[e];  // wave-uniform -> scalar load
        unsigned v = *reinterpret_cast<const unsigned*>(h + (size_t)s * F + lane * 2);
        ax += __uint_as_float((v & 0xffffu) << 16);
        ay += __uint_as_float(v & 0xffff0000u);
    }
    int deg = end - beg;
    float inv = 1.0f / (float)(deg > 0 ? deg : 1);
    unsigned r = ((unsigned)f2b(ax * inv)) | (((unsigned)f2b(ay * inv)) << 16);
    *reinterpret_cast<unsigned*>(out + (size_t)node * F + lane * 2) = r;
}

// ---------------- MFMA layer: out = A0@W0^T (+ A1@W1^T) + b ----------------
// 512 threads = 8 waves (2 row x 4 col). Block tile 128 nodes x 128 feats.
// Wave tile 64x32 = acc[4][2] fragments of 16x16. K=128 per phase, 4 steps of 32.
// No LDS: A frags direct from global bf16 (16 rows x 64B fully-consumed lines,
// L1-resident across k-steps); B (weights) preloaded to regs, L2-hot.

template <bool RELU, bool TWO, bool F32OUT>
__global__ __launch_bounds__(512) void k_layer(
        const ushort_t* __restrict__ A0, const ushort_t* __restrict__ A1,
        const ushort_t* __restrict__ W0, const ushort_t* __restrict__ W1,
        const float* __restrict__ bias, void* __restrict__ outv) {
    const int t = threadIdx.x;
    const int lane = t & 63;
    const int wid = t >> 6;
    const int wr = wid >> 2;          // 0..1
    const int wc = wid & 3;           // 0..3
    const int node0 = blockIdx.x * 128;
    const int arow = lane & 15;
    const int kgrp = lane >> 4;       // k offset = kgrp*8

    f32x4 acc[4][2];
#pragma unroll
    for (int fr = 0; fr < 4; ++fr)
#pragma unroll
        for (int fc = 0; fc < 2; ++fc) acc[fr][fc] = (f32x4)(0.f);

    const int nph = TWO ? 2 : 1;
#pragma unroll
    for (int ph = 0; ph < nph; ++ph) {
        const ushort_t* __restrict__ A = ph ? A1 : A0;
        const ushort_t* __restrict__ W = ph ? W1 : W0;

        // preload weight fragments for this phase (B operand: B[k][c] = W[c][k])
        short8 bfrag[4][2];
#pragma unroll
        for (int ks = 0; ks < 4; ++ks)
#pragma unroll
            for (int fc = 0; fc < 2; ++fc) {
                int c = wc * 32 + fc * 16 + arow;
                bfrag[ks][fc] = *reinterpret_cast<const short8*>(W + c * F + ks * 32 + kgrp * 8);
            }

#pragma unroll
        for (int ks = 0; ks < 4; ++ks) {
            short8 afrag[4];
#pragma unroll
            for (int fr = 0; fr < 4; ++fr) {
                int r = node0 + wr * 64 + fr * 16 + arow;
                if (r > N_NODES - 1) r = N_NODES - 1;
                afrag[fr] = *reinterpret_cast<const short8*>(A + (size_t)r * F + ks * 32 + kgrp * 8);
            }
#pragma unroll
            for (int fr = 0; fr < 4; ++fr)
#pragma unroll
                for (int fc = 0; fc < 2; ++fc)
                    acc[fr][fc] = __builtin_amdgcn_mfma_f32_16x16x32_bf16(
                        afrag[fr], bfrag[ks][fc], acc[fr][fc], 0, 0, 0);
        }
    }

    // epilogue: C/D layout col=lane&15, row=(lane>>4)*4+reg  [m89-verified]
#pragma unroll
    for (int fr = 0; fr < 4; ++fr)
#pragma unroll
        for (int fc = 0; fc < 2; ++fc) {
            int c = wc * 32 + fc * 16 + (lane & 15);
            float bv = bias[c];
#pragma unroll
            for (int r4 = 0; r4 < 4; ++r4) {
                int row = node0 + wr * 64 + fr * 16 + (lane >> 4) * 4 + r4;
                if (row >= N_NODES) continue;
                float v = acc[fr][fc][r4] + bv;
                if (RELU) v = fmaxf(v, 0.f);
                if (F32OUT)
                    reinterpret_cast<float*>(outv)[(size_t)row * F + c] = v;
                else
                    reinterpret_cast<ushort_t*>(outv)[(size_t)row * F + c] = f2b(v);
            }
        }
}

// ---------------- launcher ----------------

extern "C" void kernel_launch(void* const* d_in, const int* in_sizes, int n_in,
                              void* d_out, int out_size, void* d_ws, size_t ws_size,
                              hipStream_t stream) {
    const float* x   = (const float*)d_in[0];
    const int*   src = (const int*)d_in[1];
    const int*   dst = (const int*)d_in[2];
    const float* W1s = (const float*)d_in[3];
    const float* W1n = (const float*)d_in[4];
    const float* b1  = (const float*)d_in[5];
    const float* W2s = (const float*)d_in[6];
    const float* W2n = (const float*)d_in[7];
    const float* b2  = (const float*)d_in[8];
    const float* W3  = (const float*)d_in[9];
    const float* b3  = (const float*)d_in[10];
    float* out = (float*)d_out;

    // workspace layout (~84 MB)
    char* p = (char*)d_ws;
    auto align512 = [](size_t v) { return (v + 511) & ~(size_t)511; };
    int* row_ptr = (int*)p;       p += align512((N_NODES + 1) * sizeof(int));
    int* cnt     = (int*)p;       p += align512((size_t)N_NODES * sizeof(int));
    int* col     = (int*)p;       p += align512((size_t)N_EDGES * sizeof(int));
    ushort_t* wb = (ushort_t*)p;  p += align512((size_t)5 * F * F * sizeof(ushort_t));
    ushort_t* xb = (ushort_t*)p;  p += align512((size_t)N_NODES * F * sizeof(ushort_t));
    ushort_t* aggb = (ushort_t*)p; p += align512((size_t)N_NODES * F * sizeof(ushort_t));
    ushort_t* h1b  = (ushort_t*)p; p += align512((size_t)N_NODES * F * sizeof(ushort_t));
    ushort_t* h2b  = xb;  // x dead after layer 1 -> reuse

    // CSR build (in-edges keyed by dst)
    hipMemsetAsync(cnt, 0, (size_t)N_NODES * sizeof(int), stream);
    k_hist<<<(N_EDGES + 255) / 256, 256, 0, stream>>>(dst, cnt);
    k_scan<<<1, 1024, 0, stream>>>(cnt, row_ptr);
    hipMemsetAsync(cnt, 0, (size_t)N_NODES * sizeof(int), stream);
    k_fill<<<(N_EDGES + 255) / 256, 256, 0, stream>>>(src, dst, row_ptr, cnt, col);

    // bf16 conversions
    const int n8 = N_NODES * F / 8;
    k_cvt<<<(n8 + 255) / 256, 256, 0, stream>>>(x, xb, n8);
    k_cvtw<<<(5 * F * F + 255) / 256, 256, 0, stream>>>(W1s, W1n, W2s, W2n, W3, wb);

    const int agg_grid = (N_NODES + 3) / 4;          // 4 waves/block, 1 node/wave
    const int gemm_grid = (N_NODES + 127) / 128;

    // layer 1: h1 = relu(x@W1s^T + agg(x)@W1n^T + b1)
    k_agg<<<agg_grid, 256, 0, stream>>>(xb, row_ptr, col, aggb);
    k_layer<true, true, false><<<gemm_grid, 512, 0, stream>>>(
        xb, aggb, wb + 0 * F * F, wb + 1 * F * F, b1, h1b);

    // layer 2: h2 = h1@W2s^T + agg(h1)@W2n^T + b2
    k_agg<<<agg_grid, 256, 0, stream>>>(h1b, row_ptr, col, aggb);
    k_layer<false, true, false><<<gemm_grid, 512, 0, stream>>>(
        h1b, aggb, wb + 2 * F * F, wb + 3 * F * F, b2, h2b);

    // layer 3: out = h2@W3^T + b3  (f32 output)
    k_layer<false, false, true><<<gemm_grid, 512, 0, stream>>>(
        h2b, nullptr, wb + 4 * F * F, nullptr, b3, out);
}

// Round 3
// 427.349 us; speedup vs baseline: 2.5497x; 1.7829x over previous
//
#include <hip/hip_runtime.h>

#define N_NODES 100000
#define N_EDGES 1600000
#define F 128
#define NB_SCAN ((N_NODES + 1023) / 1024)   // 98

typedef short short8 __attribute__((ext_vector_type(8)));   // 8 bf16 (4 VGPR)
typedef float f32x4 __attribute__((ext_vector_type(4)));
typedef unsigned short ushort_t;
typedef ushort_t ushort8 __attribute__((ext_vector_type(8)));

__device__ __forceinline__ ushort_t f2b(float f) {
    union { float f; unsigned u; } v; v.f = f;
    unsigned r = v.u + 0x7fff + ((v.u >> 16) & 1);   // RNE
    return (ushort_t)(r >> 16);
}

// ---------------- CSR build ----------------

__global__ void k_hist(const int* __restrict__ dst, int* __restrict__ cnt) {
    int i = blockIdx.x * blockDim.x + threadIdx.x;
    if (i < N_EDGES) atomicAdd(&cnt[dst[i]], 1);
}

// hierarchical scan: pass 1 — per-block (1024) inclusive scan + block sums
__global__ __launch_bounds__(1024) void k_scan1(const int* __restrict__ cnt,
                                                int* __restrict__ tmp,
                                                int* __restrict__ bsum) {
    __shared__ int ws[16];
    const int t = threadIdx.x, lane = t & 63, w = t >> 6;
    const int gid = blockIdx.x * 1024 + t;
    int v = (gid < N_NODES) ? cnt[gid] : 0;
    int x = v;
#pragma unroll
    for (int off = 1; off < 64; off <<= 1) {
        int y = __shfl_up(x, off, 64);
        if (lane >= off) x += y;
    }
    if (lane == 63) ws[w] = x;
    __syncthreads();
    if (w == 0) {
        int s = (lane < 16) ? ws[lane] : 0;
#pragma unroll
        for (int off = 1; off < 16; off <<= 1) {
            int y = __shfl_up(s, off, 64);
            if (lane >= off) s += y;
        }
        if (lane < 16) ws[lane] = s;
    }
    __syncthreads();
    int base = (w == 0) ? 0 : ws[w - 1];
    int incl = base + x;
    if (gid < N_NODES) tmp[gid] = incl;
    if (t == 1023) bsum[blockIdx.x] = incl;
}

// pass 2 — single block: exclusive scan of NB_SCAN block sums, in place
__global__ void k_scan2(int* __restrict__ bsum) {
    const int t = threadIdx.x, lane = t & 63, w = t >> 6;
    __shared__ int ws[2];
    int v = (t < NB_SCAN) ? bsum[t] : 0;
    int x = v;
#pragma unroll
    for (int off = 1; off < 64; off <<= 1) {
        int y = __shfl_up(x, off, 64);
        if (lane >= off) x += y;
    }
    if (lane == 63) ws[w] = x;
    __syncthreads();
    int base = (w == 1) ? ws[0] : 0;
    if (t < NB_SCAN) bsum[t] = base + x - v;   // exclusive
}

// pass 3 — row_ptr[i+1] = bsum_excl[i>>10] + incl[i]; row_ptr[0] = 0
__global__ void k_scan3(const int* __restrict__ tmp, const int* __restrict__ bsum,
                        int* __restrict__ row_ptr) {
    int gid = blockIdx.x * blockDim.x + threadIdx.x;
    if (gid >= N_NODES) return;
    row_ptr[gid + 1] = bsum[gid >> 10] + tmp[gid];
    if (gid == 0) row_ptr[0] = 0;
}

__global__ void k_fill(const int* __restrict__ src, const int* __restrict__ dst,
                       const int* __restrict__ row_ptr, int* __restrict__ cursor,
                       int* __restrict__ col) {
    int i = blockIdx.x * blockDim.x + threadIdx.x;
    if (i < N_EDGES) {
        int d = dst[i];
        int pos = row_ptr[d] + atomicAdd(&cursor[d], 1);
        col[pos] = src[i];
    }
}

// ---------------- conversions / weight prep ----------------

__global__ void k_cvt(const float* __restrict__ in, ushort_t* __restrict__ out, int n8) {
    int i = blockIdx.x * blockDim.x + threadIdx.x;
    if (i >= n8) return;
    const float4* p = reinterpret_cast<const float4*>(in) + (size_t)i * 2;
    float4 a = p[0], b = p[1];
    ushort8 r;
    r[0] = f2b(a.x); r[1] = f2b(a.y); r[2] = f2b(a.z); r[3] = f2b(a.w);
    r[4] = f2b(b.x); r[5] = f2b(b.y); r[6] = f2b(b.z); r[7] = f2b(b.w);
    *reinterpret_cast<ushort8*>(out + (size_t)i * 8) = r;
}

// W1_self, W1_neigh -> bf16 slots 0,1
__global__ void k_cvtw(const float* __restrict__ a, const float* __restrict__ b,
                       ushort_t* __restrict__ out) {
    int i = blockIdx.x * blockDim.x + threadIdx.x;
    if (i >= 2 * F * F) return;
    const float* srcs[2] = {a, b};
    out[i] = f2b(srcs[i >> 14][i & (F * F - 1)]);
}

// combined weights: slot2 = W3@W2s, slot3 = W3@W2n (f32 math, bf16 out)
__global__ void k_wcomb(const float* __restrict__ W3,
                        const float* __restrict__ W2s, const float* __restrict__ W2n,
                        ushort_t* __restrict__ out) {
    const int j = threadIdx.x;          // col 0..127
    const int i = blockIdx.x & 127;     // row
    const int m = blockIdx.x >> 7;      // 0: self, 1: neigh
    const float* __restrict__ W2 = m ? W2n : W2s;
    float s = 0.f;
#pragma unroll 8
    for (int k = 0; k < F; ++k) s += W3[i * F + k] * W2[k * F + j];
    out[(size_t)m * F * F + i * F + j] = f2b(s);
}

// combined bias: bc = W3@b2 + b3
__global__ void k_bcomb(const float* __restrict__ W3, const float* __restrict__ b2,
                        const float* __restrict__ b3, float* __restrict__ bc) {
    int i = threadIdx.x;
    float s = b3[i];
#pragma unroll 8
    for (int k = 0; k < F; ++k) s += W3[i * F + k] * b2[k];
    bc[i] = s;
}

// ---------------- mean aggregation: one wave per node, bf16 rows ----------------

__global__ void k_agg(const ushort_t* __restrict__ h, const int* __restrict__ row_ptr,
                      const int* __restrict__ col, ushort_t* __restrict__ out) {
    int node = (blockIdx.x * blockDim.x + threadIdx.x) >> 6;
    if (node >= N_NODES) return;
    int lane = threadIdx.x & 63;
    int beg = row_ptr[node], end = row_ptr[node + 1];
    float ax = 0.f, ay = 0.f;
    int e = beg;
    for (; e + 4 <= end; e += 4) {       // 4 gathers in flight
        int s0 = col[e], s1 = col[e + 1], s2 = col[e + 2], s3 = col[e + 3];
        unsigned v0 = *reinterpret_cast<const unsigned*>(h + (size_t)s0 * F + lane * 2);
        unsigned v1 = *reinterpret_cast<const unsigned*>(h + (size_t)s1 * F + lane * 2);
        unsigned v2 = *reinterpret_cast<const unsigned*>(h + (size_t)s2 * F + lane * 2);
        unsigned v3 = *reinterpret_cast<const unsigned*>(h + (size_t)s3 * F + lane * 2);
        ax += __uint_as_float((v0 & 0xffffu) << 16); ay += __uint_as_float(v0 & 0xffff0000u);
        ax += __uint_as_float((v1 & 0xffffu) << 16); ay += __uint_as_float(v1 & 0xffff0000u);
        ax += __uint_as_float((v2 & 0xffffu) << 16); ay += __uint_as_float(v2 & 0xffff0000u);
        ax += __uint_as_float((v3 & 0xffffu) << 16); ay += __uint_as_float(v3 & 0xffff0000u);
    }
    for (; e < end; ++e) {
        int s = col[e];
        unsigned v = *reinterpret_cast<const unsigned*>(h + (size_t)s * F + lane * 2);
        ax += __uint_as_float((v & 0xffffu) << 16);
        ay += __uint_as_float(v & 0xffff0000u);
    }
    int deg = end - beg;
    float inv = 1.0f / (float)(deg > 0 ? deg : 1);
    unsigned r = ((unsigned)f2b(ax * inv)) | (((unsigned)f2b(ay * inv)) << 16);
    *reinterpret_cast<unsigned*>(out + (size_t)node * F + lane * 2) = r;
}

// ---------------- MFMA layer: out = A0@W0^T + A1@W1^T + b ----------------
// 512 threads = 8 waves (2 row x 4 col). Block tile 128 nodes x 128 feats.
// Wave tile 64x32 = acc[4][2] fragments of 16x16. K=128 per phase, 4 steps of 32.
// No LDS: A frags direct from global bf16; B (weights) preloaded to regs, L2-hot.

template <bool RELU, bool F32OUT>
__global__ __launch_bounds__(512) void k_layer(
        const ushort_t* __restrict__ A0, const ushort_t* __restrict__ A1,
        const ushort_t* __restrict__ W0, const ushort_t* __restrict__ W1,
        const float* __restrict__ bias, void* __restrict__ outv) {
    const int t = threadIdx.x;
    const int lane = t & 63;
    const int wid = t >> 6;
    const int wr = wid >> 2;          // 0..1
    const int wc = wid & 3;           // 0..3
    const int node0 = blockIdx.x * 128;
    const int arow = lane & 15;
    const int kgrp = lane >> 4;       // k offset = kgrp*8

    f32x4 acc[4][2];
#pragma unroll
    for (int fr = 0; fr < 4; ++fr)
#pragma unroll
        for (int fc = 0; fc < 2; ++fc) acc[fr][fc] = (f32x4)(0.f);

#pragma unroll
    for (int ph = 0; ph < 2; ++ph) {
        const ushort_t* __restrict__ A = ph ? A1 : A0;
        const ushort_t* __restrict__ W = ph ? W1 : W0;

        short8 bfrag[4][2];
#pragma unroll
        for (int ks = 0; ks < 4; ++ks)
#pragma unroll
            for (int fc = 0; fc < 2; ++fc) {
                int c = wc * 32 + fc * 16 + arow;
                bfrag[ks][fc] = *reinterpret_cast<const short8*>(W + c * F + ks * 32 + kgrp * 8);
            }

#pragma unroll
        for (int ks = 0; ks < 4; ++ks) {
            short8 afrag[4];
#pragma unroll
            for (int fr = 0; fr < 4; ++fr) {
                int r = node0 + wr * 64 + fr * 16 + arow;
                if (r > N_NODES - 1) r = N_NODES - 1;
                afrag[fr] = *reinterpret_cast<const short8*>(A + (size_t)r * F + ks * 32 + kgrp * 8);
            }
#pragma unroll
            for (int fr = 0; fr < 4; ++fr)
#pragma unroll
                for (int fc = 0; fc < 2; ++fc)
                    acc[fr][fc] = __builtin_amdgcn_mfma_f32_16x16x32_bf16(
                        afrag[fr], bfrag[ks][fc], acc[fr][fc], 0, 0, 0);
        }
    }

    // epilogue: C/D layout col=lane&15, row=(lane>>4)*4+reg  [m89-verified]
#pragma unroll
    for (int fr = 0; fr < 4; ++fr)
#pragma unroll
        for (int fc = 0; fc < 2; ++fc) {
            int c = wc * 32 + fc * 16 + (lane & 15);
            float bv = bias[c];
#pragma unroll
            for (int r4 = 0; r4 < 4; ++r4) {
                int row = node0 + wr * 64 + fr * 16 + (lane >> 4) * 4 + r4;
                if (row >= N_NODES) continue;
                float v = acc[fr][fc][r4] + bv;
                if (RELU) v = fmaxf(v, 0.f);
                if (F32OUT)
                    reinterpret_cast<float*>(outv)[(size_t)row * F + c] = v;
                else
                    reinterpret_cast<ushort_t*>(outv)[(size_t)row * F + c] = f2b(v);
            }
        }
}

// ---------------- launcher ----------------

extern "C" void kernel_launch(void* const* d_in, const int* in_sizes, int n_in,
                              void* d_out, int out_size, void* d_ws, size_t ws_size,
                              hipStream_t stream) {
    const float* x   = (const float*)d_in[0];
    const int*   src = (const int*)d_in[1];
    const int*   dst = (const int*)d_in[2];
    const float* W1s = (const float*)d_in[3];
    const float* W1n = (const float*)d_in[4];
    const float* b1  = (const float*)d_in[5];
    const float* W2s = (const float*)d_in[6];
    const float* W2n = (const float*)d_in[7];
    const float* b2  = (const float*)d_in[8];
    const float* W3  = (const float*)d_in[9];
    const float* b3  = (const float*)d_in[10];
    float* out = (float*)d_out;

    // workspace layout (~85 MB)
    char* p = (char*)d_ws;
    auto align512 = [](size_t v) { return (v + 511) & ~(size_t)511; };
    int* row_ptr = (int*)p;        p += align512((N_NODES + 1) * sizeof(int));
    int* cnt     = (int*)p;        p += align512((size_t)N_NODES * sizeof(int));
    int* stmp    = (int*)p;        p += align512((size_t)N_NODES * sizeof(int));
    int* bsum    = (int*)p;        p += align512(256 * sizeof(int));
    int* col     = (int*)p;        p += align512((size_t)N_EDGES * sizeof(int));
    ushort_t* wb = (ushort_t*)p;   p += align512((size_t)4 * F * F * sizeof(ushort_t));
    float* bc    = (float*)p;      p += align512(F * sizeof(float));
    ushort_t* xb = (ushort_t*)p;   p += align512((size_t)N_NODES * F * sizeof(ushort_t));
    ushort_t* aggb = (ushort_t*)p; p += align512((size_t)N_NODES * F * sizeof(ushort_t));
    ushort_t* h1b  = (ushort_t*)p; p += align512((size_t)N_NODES * F * sizeof(ushort_t));

    // CSR build (in-edges keyed by dst)
    hipMemsetAsync(cnt, 0, (size_t)N_NODES * sizeof(int), stream);
    k_hist<<<(N_EDGES + 255) / 256, 256, 0, stream>>>(dst, cnt);
    k_scan1<<<NB_SCAN, 1024, 0, stream>>>(cnt, stmp, bsum);
    k_scan2<<<1, 128, 0, stream>>>(bsum);
    k_scan3<<<(N_NODES + 255) / 256, 256, 0, stream>>>(stmp, bsum, row_ptr);
    hipMemsetAsync(cnt, 0, (size_t)N_NODES * sizeof(int), stream);
    k_fill<<<(N_EDGES + 255) / 256, 256, 0, stream>>>(src, dst, row_ptr, cnt, col);

    // bf16 conversions + combined layer-2/3 weights
    const int n8 = N_NODES * F / 8;
    k_cvt<<<(n8 + 255) / 256, 256, 0, stream>>>(x, xb, n8);
    k_cvtw<<<(2 * F * F + 255) / 256, 256, 0, stream>>>(W1s, W1n, wb);
    k_wcomb<<<256, 128, 0, stream>>>(W3, W2s, W2n, wb + 2 * F * F);
    k_bcomb<<<1, 128, 0, stream>>>(W3, b2, b3, bc);

    const int agg_grid = (N_NODES + 3) / 4;          // 4 waves/block, 1 node/wave
    const int gemm_grid = (N_NODES + 127) / 128;

    // layer 1: h1 = relu(x@W1s^T + agg(x)@W1n^T + b1)
    k_agg<<<agg_grid, 256, 0, stream>>>(xb, row_ptr, col, aggb);
    k_layer<true, false><<<gemm_grid, 512, 0, stream>>>(
        xb, aggb, wb + 0 * F * F, wb + 1 * F * F, b1, h1b);

    // fused layers 2+3: out = h1@(W3@W2s)^T + agg(h1)@(W3@W2n)^T + (W3@b2 + b3)
    k_agg<<<agg_grid, 256, 0, stream>>>(h1b, row_ptr, col, aggb);
    k_layer<false, true><<<gemm_grid, 512, 0, stream>>>(
        h1b, aggb, wb + 2 * F * F, wb + 3 * F * F, bc, out);
}

// Round 4
// 392.408 us; speedup vs baseline: 2.7767x; 1.0890x over previous
//
#include <hip/hip_runtime.h>

#define N_NODES 100000
#define N_EDGES 1600000
#define F 128
#define NB_SCAN ((N_NODES + 1023) / 1024)   // 98
#define NPART 8                              // one partition per XCD
#define PART_NODES (N_NODES / NPART)         // 12500 exactly
#define PBLK 104                             // blocks per partition

typedef short short8 __attribute__((ext_vector_type(8)));   // 8 bf16 (4 VGPR)
typedef float f32x4 __attribute__((ext_vector_type(4)));
typedef unsigned short ushort_t;
typedef ushort_t ushort8 __attribute__((ext_vector_type(8)));

__device__ __forceinline__ ushort_t f2b(float f) {
    union { float f; unsigned u; } v; v.f = f;
    unsigned r = v.u + 0x7fff + ((v.u >> 16) & 1);   // RNE
    return (ushort_t)(r >> 16);
}

// ---------------- CSR build (XCD-partitioned scatter) ----------------
// blockIdx.x & 7 -> XCD (round-robin dispatch). Each partition owns a
// 12.5K-node range of cnt/cursor/col: scattered writes + atomics stay in
// ONE XCD's L2 and are written back once instead of line-bouncing.

__global__ __launch_bounds__(256) void k_hist(const int* __restrict__ dst,
                                              int* __restrict__ cnt) {
    const int part = blockIdx.x & (NPART - 1);
    const int q = blockIdx.x >> 3;
    const int lo = part * PART_NODES, hi = lo + PART_NODES;
    for (int i = q * 256 + threadIdx.x; i < N_EDGES; i += PBLK * 256) {
        int d = dst[i];
        if (d >= lo && d < hi) atomicAdd(&cnt[d], 1);
    }
}

// hierarchical scan: pass 1 — per-block (1024) inclusive scan + block sums
__global__ __launch_bounds__(1024) void k_scan1(const int* __restrict__ cnt,
                                                int* __restrict__ tmp,
                                                int* __restrict__ bsum) {
    __shared__ int ws[16];
    const int t = threadIdx.x, lane = t & 63, w = t >> 6;
    const int gid = blockIdx.x * 1024 + t;
    int v = (gid < N_NODES) ? cnt[gid] : 0;
    int x = v;
#pragma unroll
    for (int off = 1; off < 64; off <<= 1) {
        int y = __shfl_up(x, off, 64);
        if (lane >= off) x += y;
    }
    if (lane == 63) ws[w] = x;
    __syncthreads();
    if (w == 0) {
        int s = (lane < 16) ? ws[lane] : 0;
#pragma unroll
        for (int off = 1; off < 16; off <<= 1) {
            int y = __shfl_up(s, off, 64);
            if (lane >= off) s += y;
        }
        if (lane < 16) ws[lane] = s;
    }
    __syncthreads();
    int base = (w == 0) ? 0 : ws[w - 1];
    int incl = base + x;
    if (gid < N_NODES) tmp[gid] = incl;
    if (t == 1023) bsum[blockIdx.x] = incl;
}

// pass 2 — single block: exclusive scan of NB_SCAN block sums, in place
__global__ void k_scan2(int* __restrict__ bsum) {
    const int t = threadIdx.x, lane = t & 63, w = t >> 6;
    __shared__ int ws[2];
    int v = (t < NB_SCAN) ? bsum[t] : 0;
    int x = v;
#pragma unroll
    for (int off = 1; off < 64; off <<= 1) {
        int y = __shfl_up(x, off, 64);
        if (lane >= off) x += y;
    }
    if (lane == 63) ws[w] = x;
    __syncthreads();
    int base = (w == 1) ? ws[0] : 0;
    if (t < NB_SCAN) bsum[t] = base + x - v;   // exclusive
}

// pass 3 — row_ptr[i+1] = bsum_excl[i>>10] + incl[i]; also zero cursor
__global__ void k_scan3(const int* __restrict__ tmp, const int* __restrict__ bsum,
                        int* __restrict__ row_ptr, int* __restrict__ cursor) {
    int gid = blockIdx.x * blockDim.x + threadIdx.x;
    if (gid >= N_NODES) return;
    row_ptr[gid + 1] = bsum[gid >> 10] + tmp[gid];
    cursor[gid] = 0;
    if (gid == 0) row_ptr[0] = 0;
}

__global__ __launch_bounds__(256) void k_fill(const int* __restrict__ src,
                                              const int* __restrict__ dst,
                                              const int* __restrict__ row_ptr,
                                              int* __restrict__ cursor,
                                              int* __restrict__ col) {
    const int part = blockIdx.x & (NPART - 1);
    const int q = blockIdx.x >> 3;
    const int lo = part * PART_NODES, hi = lo + PART_NODES;
    for (int i = q * 256 + threadIdx.x; i < N_EDGES; i += PBLK * 256) {
        int d = dst[i];
        if (d >= lo && d < hi) {
            int pos = row_ptr[d] + atomicAdd(&cursor[d], 1);
            col[pos] = src[i];
        }
    }
}

// ---------------- conversions / weight prep (single kernel) ----------------

__global__ void k_cvt(const float* __restrict__ in, ushort_t* __restrict__ out, int n8) {
    int i = blockIdx.x * blockDim.x + threadIdx.x;
    if (i >= n8) return;
    const float4* p = reinterpret_cast<const float4*>(in) + (size_t)i * 2;
    float4 a = p[0], b = p[1];
    ushort8 r;
    r[0] = f2b(a.x); r[1] = f2b(a.y); r[2] = f2b(a.z); r[3] = f2b(a.w);
    r[4] = f2b(b.x); r[5] = f2b(b.y); r[6] = f2b(b.z); r[7] = f2b(b.w);
    *reinterpret_cast<ushort8*>(out + (size_t)i * 8) = r;
}

// blocks 0..127: W1s/W1n -> bf16 slots 0,1
// blocks 128..255: slot2 = W3@W2s, slot3 = W3@W2n (f32 math, bf16 out)
// block 256: bc = W3@b2 + b3
__global__ void k_wprep(const float* __restrict__ W1s, const float* __restrict__ W1n,
                        const float* __restrict__ W2s, const float* __restrict__ W2n,
                        const float* __restrict__ W3, const float* __restrict__ b2,
                        const float* __restrict__ b3,
                        ushort_t* __restrict__ wb, float* __restrict__ bc) {
    const int b = blockIdx.x, t = threadIdx.x;
    if (b < 128) {
        int g = b * 256 + t;                 // 0..32767
        float v = (g < F * F) ? W1s[g] : W1n[g - F * F];
        wb[g] = f2b(v);
    } else if (b < 256) {
        int g = (b - 128) * 256 + t;         // 0..32767
        int m = g >> 14, rem = g & 16383, i = rem >> 7, j = rem & 127;
        const float* __restrict__ W2 = m ? W2n : W2s;
        float s = 0.f;
#pragma unroll 8
        for (int k = 0; k < F; ++k) s += W3[i * F + k] * W2[k * F + j];
        wb[2 * F * F + g] = f2b(s);
    } else if (t < F) {
        float s = b3[t];
#pragma unroll 8
        for (int k = 0; k < F; ++k) s += W3[t * F + k] * b2[k];
        bc[t] = s;
    }
}

// ---------------- mean aggregation: one wave per node, bf16 rows ----------------
// masked 8-deep gather: 8 row-loads always in flight, predicated accumulate.

__global__ void k_agg(const ushort_t* __restrict__ h, const int* __restrict__ row_ptr,
                      const int* __restrict__ col, ushort_t* __restrict__ out) {
    int node = (blockIdx.x * blockDim.x + threadIdx.x) >> 6;
    if (node >= N_NODES) return;
    int lane = threadIdx.x & 63;
    int beg = row_ptr[node], end = row_ptr[node + 1];
    float ax = 0.f, ay = 0.f;
    for (int e = beg; e < end; e += 8) {
        unsigned v[8];
#pragma unroll
        for (int u = 0; u < 8; ++u) {
            int idx = e + u; if (idx > end - 1) idx = end - 1;   // clamp (valid mem)
            int s = col[idx];                                    // wave-uniform
            v[u] = *reinterpret_cast<const unsigned*>(h + (size_t)s * F + lane * 2);
        }
#pragma unroll
        for (int u = 0; u < 8; ++u) {
            float m = (e + u < end) ? 1.f : 0.f;
            ax += m * __uint_as_float((v[u] & 0xffffu) << 16);
            ay += m * __uint_as_float(v[u] & 0xffff0000u);
        }
    }
    int deg = end - beg;
    float inv = 1.0f / (float)(deg > 0 ? deg : 1);
    unsigned r = ((unsigned)f2b(ax * inv)) | (((unsigned)f2b(ay * inv)) << 16);
    *reinterpret_cast<unsigned*>(out + (size_t)node * F + lane * 2) = r;
}

// ---------------- MFMA layer: out = A0@W0^T + A1@W1^T + b ----------------
// 512 threads = 8 waves (2 row x 4 col). Block tile 128 nodes x 128 feats.
// Wave tile 64x32 = acc[4][2] fragments of 16x16. K=128 per phase, 4 steps of 32.
// No LDS: A frags direct from global bf16; B (weights) preloaded to regs, L2-hot.

template <bool RELU, bool F32OUT>
__global__ __launch_bounds__(512) void k_layer(
        const ushort_t* __restrict__ A0, const ushort_t* __restrict__ A1,
        const ushort_t* __restrict__ W0, const ushort_t* __restrict__ W1,
        const float* __restrict__ bias, void* __restrict__ outv) {
    const int t = threadIdx.x;
    const int lane = t & 63;
    const int wid = t >> 6;
    const int wr = wid >> 2;          // 0..1
    const int wc = wid & 3;           // 0..3
    const int node0 = blockIdx.x * 128;
    const int arow = lane & 15;
    const int kgrp = lane >> 4;       // k offset = kgrp*8

    f32x4 acc[4][2];
#pragma unroll
    for (int fr = 0; fr < 4; ++fr)
#pragma unroll
        for (int fc = 0; fc < 2; ++fc) acc[fr][fc] = (f32x4)(0.f);

#pragma unroll
    for (int ph = 0; ph < 2; ++ph) {
        const ushort_t* __restrict__ A = ph ? A1 : A0;
        const ushort_t* __restrict__ W = ph ? W1 : W0;

        short8 bfrag[4][2];
#pragma unroll
        for (int ks = 0; ks < 4; ++ks)
#pragma unroll
            for (int fc = 0; fc < 2; ++fc) {
                int c = wc * 32 + fc * 16 + arow;
                bfrag[ks][fc] = *reinterpret_cast<const short8*>(W + c * F + ks * 32 + kgrp * 8);
            }

#pragma unroll
        for (int ks = 0; ks < 4; ++ks) {
            short8 afrag[4];
#pragma unroll
            for (int fr = 0; fr < 4; ++fr) {
                int r = node0 + wr * 64 + fr * 16 + arow;
                if (r > N_NODES - 1) r = N_NODES - 1;
                afrag[fr] = *reinterpret_cast<const short8*>(A + (size_t)r * F + ks * 32 + kgrp * 8);
            }
#pragma unroll
            for (int fr = 0; fr < 4; ++fr)
#pragma unroll
                for (int fc = 0; fc < 2; ++fc)
                    acc[fr][fc] = __builtin_amdgcn_mfma_f32_16x16x32_bf16(
                        afrag[fr], bfrag[ks][fc], acc[fr][fc], 0, 0, 0);
        }
    }

    // epilogue: C/D layout col=lane&15, row=(lane>>4)*4+reg  [m89-verified]
#pragma unroll
    for (int fr = 0; fr < 4; ++fr)
#pragma unroll
        for (int fc = 0; fc < 2; ++fc) {
            int c = wc * 32 + fc * 16 + (lane & 15);
            float bv = bias[c];
#pragma unroll
            for (int r4 = 0; r4 < 4; ++r4) {
                int row = node0 + wr * 64 + fr * 16 + (lane >> 4) * 4 + r4;
                if (row >= N_NODES) continue;
                float v = acc[fr][fc][r4] + bv;
                if (RELU) v = fmaxf(v, 0.f);
                if (F32OUT)
                    reinterpret_cast<float*>(outv)[(size_t)row * F + c] = v;
                else
                    reinterpret_cast<ushort_t*>(outv)[(size_t)row * F + c] = f2b(v);
            }
        }
}

// ---------------- launcher ----------------

extern "C" void kernel_launch(void* const* d_in, const int* in_sizes, int n_in,
                              void* d_out, int out_size, void* d_ws, size_t ws_size,
                              hipStream_t stream) {
    const float* x   = (const float*)d_in[0];
    const int*   src = (const int*)d_in[1];
    const int*   dst = (const int*)d_in[2];
    const float* W1s = (const float*)d_in[3];
    const float* W1n = (const float*)d_in[4];
    const float* b1  = (const float*)d_in[5];
    const float* W2s = (const float*)d_in[6];
    const float* W2n = (const float*)d_in[7];
    const float* b2  = (const float*)d_in[8];
    const float* W3  = (const float*)d_in[9];
    const float* b3  = (const float*)d_in[10];
    float* out = (float*)d_out;

    // workspace layout (~85 MB)
    char* p = (char*)d_ws;
    auto align512 = [](size_t v) { return (v + 511) & ~(size_t)511; };
    int* row_ptr = (int*)p;        p += align512((N_NODES + 1) * sizeof(int));
    int* cnt     = (int*)p;        p += align512((size_t)N_NODES * sizeof(int));
    int* stmp    = (int*)p;        p += align512((size_t)N_NODES * sizeof(int));
    int* bsum    = (int*)p;        p += align512(256 * sizeof(int));
    int* col     = (int*)p;        p += align512((size_t)N_EDGES * sizeof(int));
    ushort_t* wb = (ushort_t*)p;   p += align512((size_t)4 * F * F * sizeof(ushort_t));
    float* bc    = (float*)p;      p += align512(F * sizeof(float));
    ushort_t* xb = (ushort_t*)p;   p += align512((size_t)N_NODES * F * sizeof(ushort_t));
    ushort_t* aggb = (ushort_t*)p; p += align512((size_t)N_NODES * F * sizeof(ushort_t));
    ushort_t* h1b  = (ushort_t*)p; p += align512((size_t)N_NODES * F * sizeof(ushort_t));

    // CSR build (in-edges keyed by dst), XCD-partitioned scatters
    hipMemsetAsync(cnt, 0, (size_t)N_NODES * sizeof(int), stream);
    k_hist<<<NPART * PBLK, 256, 0, stream>>>(dst, cnt);
    k_scan1<<<NB_SCAN, 1024, 0, stream>>>(cnt, stmp, bsum);
    k_scan2<<<1, 128, 0, stream>>>(bsum);
    k_scan3<<<(N_NODES + 255) / 256, 256, 0, stream>>>(stmp, bsum, row_ptr, cnt);
    k_fill<<<NPART * PBLK, 256, 0, stream>>>(src, dst, row_ptr, cnt, col);

    // bf16 conversions + combined layer-2/3 weights
    const int n8 = N_NODES * F / 8;
    k_cvt<<<(n8 + 255) / 256, 256, 0, stream>>>(x, xb, n8);
    k_wprep<<<257, 256, 0, stream>>>(W1s, W1n, W2s, W2n, W3, b2, b3, wb, bc);

    const int agg_grid = (N_NODES + 3) / 4;          // 4 waves/block, 1 node/wave
    const int gemm_grid = (N_NODES + 127) / 128;

    // layer 1: h1 = relu(x@W1s^T + agg(x)@W1n^T + b1)
    k_agg<<<agg_grid, 256, 0, stream>>>(xb, row_ptr, col, aggb);
    k_layer<true, false><<<gemm_grid, 512, 0, stream>>>(
        xb, aggb, wb + 0 * F * F, wb + 1 * F * F, b1, h1b);

    // fused layers 2+3: out = h1@(W3@W2s)^T + agg(h1)@(W3@W2n)^T + (W3@b2 + b3)
    k_agg<<<agg_grid, 256, 0, stream>>>(h1b, row_ptr, col, aggb);
    k_layer<false, true><<<gemm_grid, 512, 0, stream>>>(
        h1b, aggb, wb + 2 * F * F, wb + 3 * F * F, bc, out);
}

// Round 5
// 339.997 us; speedup vs baseline: 3.2047x; 1.1542x over previous
//
#include <hip/hip_runtime.h>

#define N_NODES 100000
#define N_EDGES 1600000
#define F 128
#define NB_SCAN ((N_NODES + 1023) / 1024)   // 98
#define NSUB 32                              // CSR sub-partitions
#define SUB_NODES (N_NODES / NSUB)           // 3125
#define BCAP 128                             // LDS bucket capacity (pairs)
#define PCAP 65536                           // global bucket capacity (pairs)

typedef short short8 __attribute__((ext_vector_type(8)));   // 8 bf16 (4 VGPR)
typedef float f32x4 __attribute__((ext_vector_type(4)));
typedef unsigned short ushort_t;
typedef ushort_t ushort8 __attribute__((ext_vector_type(8)));

__device__ __forceinline__ ushort_t f2b(float f) {
    union { float f; unsigned u; } v; v.f = f;
    unsigned r = v.u + 0x7fff + ((v.u >> 16) & 1);   // RNE
    return (ushort_t)(r >> 16);
}

// ---------------- CSR build: bucket -> LDS hist -> scan -> LDS place ----------

// pass 0: bin edges into NSUB per-partition pair arrays via LDS staging.
// Reads (dst,src) once, writes 8B pairs coalesced. gcur[NSUB] = bump cursors.
__global__ __launch_bounds__(256) void k_bucket(const int* __restrict__ src,
                                                const int* __restrict__ dst,
                                                int2* __restrict__ pairs,
                                                int* __restrict__ gcur) {
    __shared__ int2 lbuf[NSUB * BCAP];       // 32 KB
    __shared__ int lcnt[NSUB], fbase[NSUB], fcnt[NSUB];
    const int tid = threadIdx.x;
    if (tid < NSUB) lcnt[tid] = 0;
    __syncthreads();

    for (int base = blockIdx.x * 1024; base < N_EDGES; base += gridDim.x * 1024) {
        // deposit 1024 edges (4 per thread)
#pragma unroll
        for (int r = 0; r < 4; ++r) {
            int idx = base + r * 256 + tid;
            if (idx < N_EDGES) {
                int d = dst[idx], s = src[idx];
                int p = d / SUB_NODES;               // magic-mul
                int dl = d - p * SUB_NODES;
                int slot = atomicAdd(&lcnt[p], 1);
                if (slot < BCAP) lbuf[p * BCAP + slot] = make_int2(dl, s);
                else {                               // overflow slow path (never in practice)
                    int g = atomicAdd(&gcur[p], 1);
                    pairs[(size_t)p * PCAP + g] = make_int2(dl, s);
                }
            }
        }
        __syncthreads();
        if (tid < NSUB) {
            int c = lcnt[tid]; if (c > BCAP) c = BCAP;
            fcnt[tid] = c;
            fbase[tid] = atomicAdd(&gcur[tid], c);
        }
        __syncthreads();
        // coalesced flush
        for (int p = 0; p < NSUB; ++p) {
            int c = fcnt[p];
            for (int i = tid; i < c; i += 256)
                pairs[(size_t)p * PCAP + fbase[p] + i] = lbuf[p * BCAP + i];
        }
        __syncthreads();
        if (tid < NSUB) lcnt[tid] = 0;
        __syncthreads();
    }
}

// pass 1: per-partition histogram in LDS (no device-scope atomics)
__global__ __launch_bounds__(1024) void k_histb(const int2* __restrict__ pairs,
                                                const int* __restrict__ gcur,
                                                int* __restrict__ cnt) {
    __shared__ int hc[SUB_NODES];            // 12.5 KB
    const int p = blockIdx.x;
    for (int i = threadIdx.x; i < SUB_NODES; i += 1024) hc[i] = 0;
    __syncthreads();
    const int n = gcur[p];
    const int2* __restrict__ sl = pairs + (size_t)p * PCAP;
    for (int i = threadIdx.x; i < n; i += 1024) atomicAdd(&hc[sl[i].x], 1);
    __syncthreads();
    for (int i = threadIdx.x; i < SUB_NODES; i += 1024)
        cnt[p * SUB_NODES + i] = hc[i];
}

// hierarchical scan: pass 1 — per-block (1024) inclusive scan + block sums
__global__ __launch_bounds__(1024) void k_scan1(const int* __restrict__ cnt,
                                                int* __restrict__ tmp,
                                                int* __restrict__ bsum) {
    __shared__ int ws[16];
    const int t = threadIdx.x, lane = t & 63, w = t >> 6;
    const int gid = blockIdx.x * 1024 + t;
    int v = (gid < N_NODES) ? cnt[gid] : 0;
    int x = v;
#pragma unroll
    for (int off = 1; off < 64; off <<= 1) {
        int y = __shfl_up(x, off, 64);
        if (lane >= off) x += y;
    }
    if (lane == 63) ws[w] = x;
    __syncthreads();
    if (w == 0) {
        int s = (lane < 16) ? ws[lane] : 0;
#pragma unroll
        for (int off = 1; off < 16; off <<= 1) {
            int y = __shfl_up(s, off, 64);
            if (lane >= off) s += y;
        }
        if (lane < 16) ws[lane] = s;
    }
    __syncthreads();
    int base = (w == 0) ? 0 : ws[w - 1];
    int incl = base + x;
    if (gid < N_NODES) tmp[gid] = incl;
    if (t == 1023) bsum[blockIdx.x] = incl;
}

__global__ void k_scan2(int* __restrict__ bsum) {
    const int t = threadIdx.x, lane = t & 63, w = t >> 6;
    __shared__ int ws[2];
    int v = (t < NB_SCAN) ? bsum[t] : 0;
    int x = v;
#pragma unroll
    for (int off = 1; off < 64; off <<= 1) {
        int y = __shfl_up(x, off, 64);
        if (lane >= off) x += y;
    }
    if (lane == 63) ws[w] = x;
    __syncthreads();
    int base = (w == 1) ? ws[0] : 0;
    if (t < NB_SCAN) bsum[t] = base + x - v;   // exclusive
}

__global__ void k_scan3(const int* __restrict__ tmp, const int* __restrict__ bsum,
                        int* __restrict__ row_ptr) {
    int gid = blockIdx.x * blockDim.x + threadIdx.x;
    if (gid >= N_NODES) return;
    row_ptr[gid + 1] = bsum[gid >> 10] + tmp[gid];
    if (gid == 0) row_ptr[0] = 0;
}

// pass 2: per-partition placement via LDS cursors; col scatter confined to
// one ~400KB window per block -> L2-resident, written back once.
__global__ __launch_bounds__(1024) void k_place(const int2* __restrict__ pairs,
                                                const int* __restrict__ gcur,
                                                const int* __restrict__ row_ptr,
                                                int* __restrict__ col) {
    __shared__ int cur[SUB_NODES];           // 12.5 KB
    const int p = blockIdx.x;
    for (int i = threadIdx.x; i < SUB_NODES; i += 1024)
        cur[i] = row_ptr[p * SUB_NODES + i];
    __syncthreads();
    const int n = gcur[p];
    const int2* __restrict__ sl = pairs + (size_t)p * PCAP;
    for (int i = threadIdx.x; i < n; i += 1024) {
        int2 pr = sl[i];
        int pos = atomicAdd(&cur[pr.x], 1);
        col[pos] = pr.y;
    }
}

// ---------------- conversions / weight prep ----------------

__global__ void k_cvt(const float* __restrict__ in, ushort_t* __restrict__ out, int n8) {
    int i = blockIdx.x * blockDim.x + threadIdx.x;
    if (i >= n8) return;
    const float4* p = reinterpret_cast<const float4*>(in) + (size_t)i * 2;
    float4 a = p[0], b = p[1];
    ushort8 r;
    r[0] = f2b(a.x); r[1] = f2b(a.y); r[2] = f2b(a.z); r[3] = f2b(a.w);
    r[4] = f2b(b.x); r[5] = f2b(b.y); r[6] = f2b(b.z); r[7] = f2b(b.w);
    *reinterpret_cast<ushort8*>(out + (size_t)i * 8) = r;
}

// blocks 0..127: W1s/W1n -> bf16 slots 0,1
// blocks 128..255: slot2 = W3@W2s, slot3 = W3@W2n (f32 math, bf16 out)
// block 256: bc = W3@b2 + b3
__global__ void k_wprep(const float* __restrict__ W1s, const float* __restrict__ W1n,
                        const float* __restrict__ W2s, const float* __restrict__ W2n,
                        const float* __restrict__ W3, const float* __restrict__ b2,
                        const float* __restrict__ b3,
                        ushort_t* __restrict__ wb, float* __restrict__ bc) {
    const int b = blockIdx.x, t = threadIdx.x;
    if (b < 128) {
        int g = b * 256 + t;
        float v = (g < F * F) ? W1s[g] : W1n[g - F * F];
        wb[g] = f2b(v);
    } else if (b < 256) {
        int g = (b - 128) * 256 + t;
        int m = g >> 14, rem = g & 16383, i = rem >> 7, j = rem & 127;
        const float* __restrict__ W2 = m ? W2n : W2s;
        float s = 0.f;
#pragma unroll 8
        for (int k = 0; k < F; ++k) s += W3[i * F + k] * W2[k * F + j];
        wb[2 * F * F + g] = f2b(s);
    } else if (t < F) {
        float s = b3[t];
#pragma unroll 8
        for (int k = 0; k < F; ++k) s += W3[t * F + k] * b2[k];
        bc[t] = s;
    }
}

// ---------------- mean aggregation: one wave per node, bf16 rows ----------------

__global__ void k_agg(const ushort_t* __restrict__ h, const int* __restrict__ row_ptr,
                      const int* __restrict__ col, ushort_t* __restrict__ out) {
    int node = (blockIdx.x * blockDim.x + threadIdx.x) >> 6;
    if (node >= N_NODES) return;
    int lane = threadIdx.x & 63;
    int beg = row_ptr[node], end = row_ptr[node + 1];
    float ax = 0.f, ay = 0.f;
    for (int e = beg; e < end; e += 8) {
        unsigned v[8];
#pragma unroll
        for (int u = 0; u < 8; ++u) {
            int idx = e + u; if (idx > end - 1) idx = end - 1;   // clamp (valid mem)
            int s = col[idx];                                    // wave-uniform
            v[u] = *reinterpret_cast<const unsigned*>(h + (size_t)s * F + lane * 2);
        }
#pragma unroll
        for (int u = 0; u < 8; ++u) {
            float m = (e + u < end) ? 1.f : 0.f;
            ax += m * __uint_as_float((v[u] & 0xffffu) << 16);
            ay += m * __uint_as_float(v[u] & 0xffff0000u);
        }
    }
    int deg = end - beg;
    float inv = 1.0f / (float)(deg > 0 ? deg : 1);
    unsigned r = ((unsigned)f2b(ax * inv)) | (((unsigned)f2b(ay * inv)) << 16);
    *reinterpret_cast<unsigned*>(out + (size_t)node * F + lane * 2) = r;
}

// ---------------- MFMA layer: out = A0@W0^T + A1@W1^T + b ----------------

template <bool RELU, bool F32OUT>
__global__ __launch_bounds__(512) void k_layer(
        const ushort_t* __restrict__ A0, const ushort_t* __restrict__ A1,
        const ushort_t* __restrict__ W0, const ushort_t* __restrict__ W1,
        const float* __restrict__ bias, void* __restrict__ outv) {
    const int t = threadIdx.x;
    const int lane = t & 63;
    const int wid = t >> 6;
    const int wr = wid >> 2;          // 0..1
    const int wc = wid & 3;           // 0..3
    const int node0 = blockIdx.x * 128;
    const int arow = lane & 15;
    const int kgrp = lane >> 4;       // k offset = kgrp*8

    f32x4 acc[4][2];
#pragma unroll
    for (int fr = 0; fr < 4; ++fr)
#pragma unroll
        for (int fc = 0; fc < 2; ++fc) acc[fr][fc] = (f32x4)(0.f);

#pragma unroll
    for (int ph = 0; ph < 2; ++ph) {
        const ushort_t* __restrict__ A = ph ? A1 : A0;
        const ushort_t* __restrict__ W = ph ? W1 : W0;

        short8 bfrag[4][2];
#pragma unroll
        for (int ks = 0; ks < 4; ++ks)
#pragma unroll
            for (int fc = 0; fc < 2; ++fc) {
                int c = wc * 32 + fc * 16 + arow;
                bfrag[ks][fc] = *reinterpret_cast<const short8*>(W + c * F + ks * 32 + kgrp * 8);
            }

#pragma unroll
        for (int ks = 0; ks < 4; ++ks) {
            short8 afrag[4];
#pragma unroll
            for (int fr = 0; fr < 4; ++fr) {
                int r = node0 + wr * 64 + fr * 16 + arow;
                if (r > N_NODES - 1) r = N_NODES - 1;
                afrag[fr] = *reinterpret_cast<const short8*>(A + (size_t)r * F + ks * 32 + kgrp * 8);
            }
#pragma unroll
            for (int fr = 0; fr < 4; ++fr)
#pragma unroll
                for (int fc = 0; fc < 2; ++fc)
                    acc[fr][fc] = __builtin_amdgcn_mfma_f32_16x16x32_bf16(
                        afrag[fr], bfrag[ks][fc], acc[fr][fc], 0, 0, 0);
        }
    }

    // epilogue: C/D layout col=lane&15, row=(lane>>4)*4+reg  [m89-verified]
#pragma unroll
    for (int fr = 0; fr < 4; ++fr)
#pragma unroll
        for (int fc = 0; fc < 2; ++fc) {
            int c = wc * 32 + fc * 16 + (lane & 15);
            float bv = bias[c];
#pragma unroll
            for (int r4 = 0; r4 < 4; ++r4) {
                int row = node0 + wr * 64 + fr * 16 + (lane >> 4) * 4 + r4;
                if (row >= N_NODES) continue;
                float v = acc[fr][fc][r4] + bv;
                if (RELU) v = fmaxf(v, 0.f);
                if (F32OUT)
                    reinterpret_cast<float*>(outv)[(size_t)row * F + c] = v;
                else
                    reinterpret_cast<ushort_t*>(outv)[(size_t)row * F + c] = f2b(v);
            }
        }
}

// ---------------- launcher ----------------

extern "C" void kernel_launch(void* const* d_in, const int* in_sizes, int n_in,
                              void* d_out, int out_size, void* d_ws, size_t ws_size,
                              hipStream_t stream) {
    const float* x   = (const float*)d_in[0];
    const int*   src = (const int*)d_in[1];
    const int*   dst = (const int*)d_in[2];
    const float* W1s = (const float*)d_in[3];
    const float* W1n = (const float*)d_in[4];
    const float* b1  = (const float*)d_in[5];
    const float* W2s = (const float*)d_in[6];
    const float* W2n = (const float*)d_in[7];
    const float* b2  = (const float*)d_in[8];
    const float* W3  = (const float*)d_in[9];
    const float* b3  = (const float*)d_in[10];
    float* out = (float*)d_out;

    // workspace layout (~85 MB)
    char* p = (char*)d_ws;
    auto align512 = [](size_t v) { return (v + 511) & ~(size_t)511; };
    int* row_ptr = (int*)p;        p += align512((N_NODES + 1) * sizeof(int));
    int* cnt     = (int*)p;        p += align512((size_t)N_NODES * sizeof(int));
    int* stmp    = (int*)p;        p += align512((size_t)N_NODES * sizeof(int));
    int* bsum    = (int*)p;        p += align512(256 * sizeof(int));
    int* gcur    = (int*)p;        p += align512(NSUB * sizeof(int));
    int* col     = (int*)p;        p += align512((size_t)N_EDGES * sizeof(int));
    ushort_t* wb = (ushort_t*)p;   p += align512((size_t)4 * F * F * sizeof(ushort_t));
    float* bc    = (float*)p;      p += align512(F * sizeof(float));
    ushort_t* xb = (ushort_t*)p;   p += align512((size_t)N_NODES * F * sizeof(ushort_t));
    ushort_t* aggb = (ushort_t*)p; p += align512((size_t)N_NODES * F * sizeof(ushort_t));
    ushort_t* h1b  = (ushort_t*)p; p += align512((size_t)N_NODES * F * sizeof(ushort_t));
    // pairs (16 MB) aliases aggb (25.6 MB): dead before first k_agg writes aggb
    int2* pairs = (int2*)aggb;

    // CSR build: bucket -> LDS hist -> scan -> LDS place
    hipMemsetAsync(gcur, 0, NSUB * sizeof(int), stream);
    k_bucket<<<512, 256, 0, stream>>>(src, dst, pairs, gcur);
    k_histb<<<NSUB, 1024, 0, stream>>>(pairs, gcur, cnt);
    k_scan1<<<NB_SCAN, 1024, 0, stream>>>(cnt, stmp, bsum);
    k_scan2<<<1, 128, 0, stream>>>(bsum);
    k_scan3<<<(N_NODES + 255) / 256, 256, 0, stream>>>(stmp, bsum, row_ptr);
    k_place<<<NSUB, 1024, 0, stream>>>(pairs, gcur, row_ptr, col);

    // bf16 conversions + combined layer-2/3 weights
    const int n8 = N_NODES * F / 8;
    k_cvt<<<(n8 + 255) / 256, 256, 0, stream>>>(x, xb, n8);
    k_wprep<<<257, 256, 0, stream>>>(W1s, W1n, W2s, W2n, W3, b2, b3, wb, bc);

    const int agg_grid = (N_NODES + 3) / 4;          // 4 waves/block, 1 node/wave
    const int gemm_grid = (N_NODES + 127) / 128;

    // layer 1: h1 = relu(x@W1s^T + agg(x)@W1n^T + b1)
    k_agg<<<agg_grid, 256, 0, stream>>>(xb, row_ptr, col, aggb);
    k_layer<true, false><<<gemm_grid, 512, 0, stream>>>(
        xb, aggb, wb + 0 * F * F, wb + 1 * F * F, b1, h1b);

    // fused layers 2+3: out = h1@(W3@W2s)^T + agg(h1)@(W3@W2n)^T + (W3@b2 + b3)
    k_agg<<<agg_grid, 256, 0, stream>>>(h1b, row_ptr, col, aggb);
    k_layer<false, true><<<gemm_grid, 512, 0, stream>>>(
        h1b, aggb, wb + 2 * F * F, wb + 3 * F * F, bc, out);
}